// Round 7
// baseline (1512.836 us; speedup 1.0000x reference)
//
#include <hip/hip_runtime.h>
#include <math.h>

#define D 64
#define EPS 1e-12f
#define LN_EPS 1e-5f
#define NT 64   // nodes per block in node_linears

// ---------------------------------------------------------------------------
// Kernel A: per-node linears, tile-parallel (structure verified R3/R4).
// Emits PACKED pairs for the edge passes:
//   P1[n*64+d] = {B1h, sigmaQ}   (gathered by src)
//   P2[n*64+d] = {B2h, sigmaK}   (gathered by dst)
//   P3[n*64+d] = {vh,  C2p }     (gathered by src; .x also used in epilogue)
//   C1p[n*64+d]                  (epilogue only)
// ---------------------------------------------------------------------------
__global__ void __launch_bounds__(256, 2)
node_linears(const float* __restrict__ h, const float* __restrict__ p,
             const float* __restrict__ WK, const float* __restrict__ bK,
             const float* __restrict__ WV, const float* __restrict__ bV,
             const float* __restrict__ WB1, const float* __restrict__ bB1,
             const float* __restrict__ WB2, const float* __restrict__ bB2,
             const float* __restrict__ WC1, const float* __restrict__ bC1,
             const float* __restrict__ WC2, const float* __restrict__ bC2,
             float2* __restrict__ P1, float2* __restrict__ P2,
             float2* __restrict__ P3, float* __restrict__ C1pA, int N)
{
    __shared__ float xs[NT * 128];    // [n][k], k<64 = h, k>=64 = p
    __shared__ float wsm[64 * 128];   // phase weight buffer, f4-swizzled

    const int t = threadIdx.x;
    const int lane = t & 63;
    const int wid = t >> 6;
    const int n0 = blockIdx.x * NT;

    float4* xs4 = (float4*)xs;
    float4* wsm4 = (float4*)wsm;

    {
        const float4* h4 = (const float4*)h;
        const float4* p4 = (const float4*)p;
        for (int i = t; i < NT * 32; i += 256) {
            int n = i >> 5, kq = i & 31;
            int ng = n0 + n;
            float4 v = make_float4(0.f, 0.f, 0.f, 0.f);
            if (ng < N) v = (kq < 16) ? h4[(size_t)ng * 16 + kq]
                                      : p4[(size_t)ng * 16 + (kq - 16)];
            xs4[n * 32 + kq] = v;
        }
    }
    __syncthreads();

#define STAGE_W128(W)                                                    \
    {                                                                    \
        const float4* w4 = (const float4*)(W);                           \
        for (int i = t; i < 64 * 32; i += 256) {                         \
            int d = i >> 5, j = i & 31;                                  \
            wsm4[d * 32 + (j ^ (d & 31))] = w4[i];                       \
        }                                                                \
    }                                                                    \
    __syncthreads();

#define LOAD_ROW128(wreg)                                                \
    _Pragma("unroll")                                                    \
    for (int j = 0; j < 32; ++j) wreg[j] = wsm4[lane * 32 + (j ^ (lane & 31))];

    // ---- WK phase: sigmaQ -> P1.y, sigmaK -> P2.y ----
    {
        STAGE_W128(WK);
        float4 w[32];
        LOAD_ROW128(w);
        float bk = bK[lane];
#pragma unroll 1
        for (int i = 0; i < 16; ++i) {
            int n = wid * 16 + i;
            const float4* xv = (const float4*)&xs[n * 128];
            float a0 = 0.f, a1 = 0.f, a2 = 0.f, a3 = 0.f;
#pragma unroll
            for (int j = 0; j < 32; j += 4) {
                float4 x0 = xv[j + 0], x1 = xv[j + 1], x2 = xv[j + 2], x3 = xv[j + 3];
                a0 += w[j+0].x*x0.x + w[j+0].y*x0.y + w[j+0].z*x0.z + w[j+0].w*x0.w;
                a1 += w[j+1].x*x1.x + w[j+1].y*x1.y + w[j+1].z*x1.z + w[j+1].w*x1.w;
                a2 += w[j+2].x*x2.x + w[j+2].y*x2.y + w[j+2].z*x2.z + w[j+2].w*x2.w;
                a3 += w[j+3].x*x3.x + w[j+3].y*x3.y + w[j+3].z*x3.z + w[j+3].w*x3.w;
            }
            float aq = bk + (a0 + a1) + (a2 + a3);
            int ng = n0 + n;
            if (ng < N) {
                size_t o = (size_t)ng * 64 + lane;
                P1[o].y = expf(tanhf(aq));
                P2[o].y = expf(1.f / (1.f + expf(-aq)));
            }
        }
        __syncthreads();
    }

    // ---- WV phase: vh -> P3.x ----
    {
        STAGE_W128(WV);
        float4 w[32];
        LOAD_ROW128(w);
        float bv = bV[lane];
#pragma unroll 1
        for (int i = 0; i < 16; ++i) {
            int n = wid * 16 + i;
            const float4* xv = (const float4*)&xs[n * 128];
            float a0 = 0.f, a1 = 0.f, a2 = 0.f, a3 = 0.f;
#pragma unroll
            for (int j = 0; j < 32; j += 4) {
                float4 x0 = xv[j + 0], x1 = xv[j + 1], x2 = xv[j + 2], x3 = xv[j + 3];
                a0 += w[j+0].x*x0.x + w[j+0].y*x0.y + w[j+0].z*x0.z + w[j+0].w*x0.w;
                a1 += w[j+1].x*x1.x + w[j+1].y*x1.y + w[j+1].z*x1.z + w[j+1].w*x1.w;
                a2 += w[j+2].x*x2.x + w[j+2].y*x2.y + w[j+2].z*x2.z + w[j+2].w*x2.w;
                a3 += w[j+3].x*x3.x + w[j+3].y*x3.y + w[j+3].z*x3.z + w[j+3].w*x3.w;
            }
            float av = bv + (a0 + a1) + (a2 + a3);
            int ng = n0 + n;
            if (ng < N) P3[(size_t)ng * 64 + lane].x = av;
        }
        __syncthreads();
    }

#define STAGE_W64x2(WA, WB)                                              \
    {                                                                    \
        for (int i = t; i < 2048; i += 256) {                            \
            int m = i >> 10;                                             \
            int r = i & 1023;                                            \
            int d = r >> 4, j = r & 15;                                  \
            const float4* w4 = m ? (const float4*)(WB) : (const float4*)(WA); \
            wsm4[m * 1024 + d * 16 + (j ^ (d & 15))] = w4[r];            \
        }                                                                \
    }                                                                    \
    __syncthreads();

    // ---- WB1/WB2 phase (input h): B1h -> P1.x, B2h -> P2.x ----
    {
        STAGE_W64x2(WB1, WB2);
        float4 w1[16], w2[16];
#pragma unroll
        for (int j = 0; j < 16; ++j) {
            w1[j] = wsm4[lane * 16 + (j ^ (lane & 15))];
            w2[j] = wsm4[1024 + lane * 16 + (j ^ (lane & 15))];
        }
        float b1 = bB1[lane], b2 = bB2[lane];
#pragma unroll 1
        for (int i = 0; i < 16; ++i) {
            int n = wid * 16 + i;
            const float4* xv = (const float4*)&xs[n * 128];
            float a0 = 0.f, a1 = 0.f, c0 = 0.f, c1 = 0.f;
#pragma unroll
            for (int j = 0; j < 16; j += 2) {
                float4 x0 = xv[j], x1 = xv[j + 1];
                a0 += w1[j].x*x0.x + w1[j].y*x0.y + w1[j].z*x0.z + w1[j].w*x0.w;
                a1 += w1[j+1].x*x1.x + w1[j+1].y*x1.y + w1[j+1].z*x1.z + w1[j+1].w*x1.w;
                c0 += w2[j].x*x0.x + w2[j].y*x0.y + w2[j].z*x0.z + w2[j].w*x0.w;
                c1 += w2[j+1].x*x1.x + w2[j+1].y*x1.y + w2[j+1].z*x1.z + w2[j+1].w*x1.w;
            }
            int ng = n0 + n;
            if (ng < N) {
                size_t o = (size_t)ng * 64 + lane;
                P1[o].x = b1 + a0 + a1;
                P2[o].x = b2 + c0 + c1;
            }
        }
        __syncthreads();
    }

    // ---- WC1/WC2 phase (input p): C1p -> array, C2p -> P3.y ----
    {
        STAGE_W64x2(WC1, WC2);
        float4 w1[16], w2[16];
#pragma unroll
        for (int j = 0; j < 16; ++j) {
            w1[j] = wsm4[lane * 16 + (j ^ (lane & 15))];
            w2[j] = wsm4[1024 + lane * 16 + (j ^ (lane & 15))];
        }
        float b1 = bC1[lane], b2 = bC2[lane];
#pragma unroll 1
        for (int i = 0; i < 16; ++i) {
            int n = wid * 16 + i;
            const float4* xv = (const float4*)&xs[n * 128 + 64];
            float a0 = 0.f, a1 = 0.f, c0 = 0.f, c1 = 0.f;
#pragma unroll
            for (int j = 0; j < 16; j += 2) {
                float4 x0 = xv[j], x1 = xv[j + 1];
                a0 += w1[j].x*x0.x + w1[j].y*x0.y + w1[j].z*x0.z + w1[j].w*x0.w;
                a1 += w1[j+1].x*x1.x + w1[j+1].y*x1.y + w1[j+1].z*x1.z + w1[j+1].w*x1.w;
                c0 += w2[j].x*x0.x + w2[j].y*x0.y + w2[j].z*x0.z + w2[j].w*x0.w;
                c1 += w2[j+1].x*x1.x + w2[j+1].y*x1.y + w2[j+1].z*x1.z + w2[j+1].w*x1.w;
            }
            int ng = n0 + n;
            if (ng < N) {
                size_t o = (size_t)ng * 64 + lane;
                C1pA[o] = b1 + a0 + a1;
                P3[o].y = b2 + c0 + c1;
            }
        }
    }
}

// ---------------------------------------------------------------------------
// dst-bucketing pipeline (int atomics only; unchanged -- verified R4).
// ---------------------------------------------------------------------------
__global__ void hist_kernel(const int* __restrict__ dst, int* __restrict__ cnt, int E) {
    int i = blockIdx.x * blockDim.x + threadIdx.x;
    if (i < E) atomicAdd(&cnt[dst[i]], 1);
}

__global__ void chunksum_kernel(const int* __restrict__ cnt, int* __restrict__ csum, int N) {
    __shared__ int sc[256];
    int t = threadIdx.x;
    int i = blockIdx.x * 256 + t;
    sc[t] = (i < N) ? cnt[i] : 0;
    __syncthreads();
    for (int off = 128; off > 0; off >>= 1) {
        if (t < off) sc[t] += sc[t + off];
        __syncthreads();
    }
    if (t == 0) csum[blockIdx.x] = sc[0];
}

__global__ void scanchunk_kernel(int* __restrict__ csum, int nch) {
    __shared__ int sc[256];
    int t = threadIdx.x;
    int v = (t < nch) ? csum[t] : 0;
    sc[t] = v;
    __syncthreads();
    for (int off = 1; off < 256; off <<= 1) {
        int y = (t >= off) ? sc[t - off] : 0;
        __syncthreads();
        sc[t] += y;
        __syncthreads();
    }
    if (t < nch) csum[t] = sc[t] - v;   // exclusive prefix
}

__global__ void offsets_kernel(const int* __restrict__ cnt, const int* __restrict__ csum,
                               int* __restrict__ offs, int N) {
    __shared__ int sc[256];
    int t = threadIdx.x;
    int i = blockIdx.x * 256 + t;
    int v = (i < N) ? cnt[i] : 0;
    sc[t] = v;
    __syncthreads();
    for (int off = 1; off < 256; off <<= 1) {
        int y = (t >= off) ? sc[t - off] : 0;
        __syncthreads();
        sc[t] += y;
        __syncthreads();
    }
    if (i < N) offs[i] = csum[blockIdx.x] + sc[t] - v;  // global exclusive prefix
}

__global__ void scatter_kernel(const int* __restrict__ dst, int* __restrict__ offs,
                               int* __restrict__ bucket, int E) {
    int i = blockIdx.x * blockDim.x + threadIdx.x;
    if (i < E) {
        int pos = atomicAdd(&offs[dst[i]], 1);
        bucket[pos] = i;
    }
}

// ---------------------------------------------------------------------------
// Kernel B: edge compute, wave-per-edge-pair (ILP=2). lane = feature dim.
// __launch_bounds__(256,8): 8 waves/SIMD (VGPR cap 64 >= measured 52).
// R6 ran at 3.2 waves/SIMD (self-capped at 4/EU) with VALUBusy 36% --
// latency-bound on the src->P1 gather chain; more resident waves hide it.
// ---------------------------------------------------------------------------
__global__ void __launch_bounds__(256, 8)
edge_compute(const float* __restrict__ e, const int* __restrict__ src,
             const int* __restrict__ dst,
             const float* __restrict__ WB3, const float* __restrict__ bB3,
             const float2* __restrict__ P1, const float2* __restrict__ P2,
             float* __restrict__ he_out, float* __restrict__ alpha, int E)
{
    const int lane = threadIdx.x & 63;
    const int wid = __builtin_amdgcn_readfirstlane((int)(threadIdx.x >> 6));
    const int wpb = blockDim.x >> 6;
    const int gw = blockIdx.x * wpb + wid;
    const int nw = gridDim.x * wpb;

    float4 wb3[16];
    const float4* w4 = (const float4*)(WB3 + (size_t)lane * D);
#pragma unroll
    for (int j = 0; j < 16; ++j) wb3[j] = w4[j];
    const float bb3 = bB3[lane];

    for (int ed = gw * 2; ed < E; ed += nw * 2) {
        const bool two = (ed + 1 < E);
        int s0 = src[ed];
        int t0 = dst[ed];
        int s1 = two ? src[ed + 1] : s0;
        int t1 = two ? dst[ed + 1] : t0;

        // gathers for both edges (independent, issue early)
        float2 a0 = P1[(size_t)s0 * D + lane];   // {B1h, sigmaQ}
        float2 b0 = P2[(size_t)t0 * D + lane];   // {B2h, sigmaK}
        float2 a1 = P1[(size_t)s1 * D + lane];
        float2 b1 = P2[(size_t)t1 * D + lane];

        // both e-rows, interleaved matvec
        const float4* er0 = (const float4*)(e + (size_t)ed * D);
        const float4* er1 = two ? (const float4*)(e + (size_t)(ed + 1) * D) : er0;
        float h0 = bb3, h1 = bb3;
#pragma unroll
        for (int j = 0; j < 16; ++j) {
            float4 e0 = er0[j];
            float4 e1 = er1[j];
            h0 += e0.x*wb3[j].x + e0.y*wb3[j].y + e0.z*wb3[j].z + e0.w*wb3[j].w;
            h1 += e1.x*wb3[j].x + e1.y*wb3[j].y + e1.z*wb3[j].z + e1.w*wb3[j].w;
        }

        float he0 = a0.x + b0.x + h0;
        float he1 = a1.x + b1.x + h1;
        he_out[(size_t)ed * D + lane] = he0;
        if (two) he_out[(size_t)(ed + 1) * D + lane] = he1;

        float p0 = a0.y * b0.y;
        float p1 = a1.y * b1.y;
#pragma unroll
        for (int off = 32; off > 0; off >>= 1) {
            p0 += __shfl_xor(p0, off);
            p1 += __shfl_xor(p1, off);
        }
        if (lane == 0) {
            alpha[ed] = p0;
            if (two) alpha[ed + 1] = p1;
        }
    }
}

// ---------------------------------------------------------------------------
// Kernel C: gather + finalize, wave-per-node, ILP=2 on the bucket walk.
// __launch_bounds__(256,6): raise TLP (same latency-hiding argument).
// ---------------------------------------------------------------------------
__global__ void __launch_bounds__(256, 6)
gather_finalize(const int* __restrict__ bucket, const int* __restrict__ offs_end,
                const int* __restrict__ cnt, const int* __restrict__ src,
                const float* __restrict__ alpha,
                const float2* __restrict__ P3, const float* __restrict__ C1pA,
                const float* __restrict__ ln_g, const float* __restrict__ ln_b,
                float* __restrict__ he_eout, float* __restrict__ h_out,
                float* __restrict__ p_out, int N)
{
    const int lane = threadIdx.x & 63;
    const int wid = threadIdx.x >> 6;
    const int wpb = blockDim.x >> 6;
    const float lg = ln_g[lane], lb = ln_b[lane];

    for (int n = blockIdx.x * wpb + wid; n < N; n += gridDim.x * wpb) {
        const int end = offs_end[n];
        const int deg = cnt[n];
        const int start = end - deg;
        const size_t o = (size_t)n * D + lane;

        float asig = 0.f, av = 0.f, ap = 0.f;

        int k = start;
        for (; k + 1 < end; k += 2) {
            int e0 = __builtin_amdgcn_readfirstlane(bucket[k]);
            int e1 = __builtin_amdgcn_readfirstlane(bucket[k + 1]);
            int s0 = __builtin_amdgcn_readfirstlane(src[e0]);
            int s1 = __builtin_amdgcn_readfirstlane(src[e1]);
            float al0 = alpha[e0];
            float al1 = alpha[e1];
            size_t eo0 = (size_t)e0 * D + lane;
            size_t eo1 = (size_t)e1 * D + lane;
            float he0 = he_eout[eo0];
            float he1 = he_eout[eo1];
            float2 v0 = P3[(size_t)s0 * D + lane];   // {vh, C2p}
            float2 v1 = P3[(size_t)s1 * D + lane];

            he_eout[eo0] = fmaxf(he0, 0.f);
            he_eout[eo1] = fmaxf(he1, 0.f);
            float sg0 = 1.f / (1.f + expf(-he0));
            float sg1 = 1.f / (1.f + expf(-he1));
            asig += sg0 + sg1;
            av   += sg0 * al0 * v0.x + sg1 * al1 * v1.x;
            ap   += sg0 * v0.y + sg1 * v1.y;
        }
        if (k < end) {
            int e0 = __builtin_amdgcn_readfirstlane(bucket[k]);
            int s0 = __builtin_amdgcn_readfirstlane(src[e0]);
            float al0 = alpha[e0];
            size_t eo0 = (size_t)e0 * D + lane;
            float he0 = he_eout[eo0];
            float2 v0 = P3[(size_t)s0 * D + lane];
            he_eout[eo0] = fmaxf(he0, 0.f);
            float sg0 = 1.f / (1.f + expf(-he0));
            asig += sg0;
            av   += sg0 * al0 * v0.x;
            ap   += sg0 * v0.y;
        }

        // fused epilogue
        float denom = asig + EPS;
        float hv = P3[o].x + av / denom;
        hv = fmaxf(hv, 0.f);
        float su = hv;
#pragma unroll
        for (int off = 32; off > 0; off >>= 1) su += __shfl_xor(su, off);
        float mu = su * (1.f / 64.f);
        float dv = hv - mu;
        float s2 = dv * dv;
#pragma unroll
        for (int off = 32; off > 0; off >>= 1) s2 += __shfl_xor(s2, off);
        float var = s2 * (1.f / 64.f);
        h_out[o] = dv * rsqrtf(var + LN_EPS) * lg + lb;

        float pv = C1pA[o] + ap / denom;
        p_out[o] = tanhf(pv);
    }
}

extern "C" void kernel_launch(void* const* d_in, const int* in_sizes, int n_in,
                              void* d_out, int out_size, void* d_ws, size_t ws_size,
                              hipStream_t stream) {
    const float* h    = (const float*)d_in[0];
    const float* e    = (const float*)d_in[1];
    const float* p    = (const float*)d_in[2];
    const float* WK   = (const float*)d_in[3];
    const float* bK   = (const float*)d_in[4];
    const float* WV   = (const float*)d_in[5];
    const float* bV   = (const float*)d_in[6];
    const float* WB1  = (const float*)d_in[7];
    const float* bB1  = (const float*)d_in[8];
    const float* WB2  = (const float*)d_in[9];
    const float* bB2  = (const float*)d_in[10];
    const float* WB3  = (const float*)d_in[11];
    const float* bB3  = (const float*)d_in[12];
    const float* WC1  = (const float*)d_in[13];
    const float* bC1  = (const float*)d_in[14];
    const float* WC2  = (const float*)d_in[15];
    const float* bC2  = (const float*)d_in[16];
    const float* ln_g = (const float*)d_in[17];
    const float* ln_b = (const float*)d_in[18];
    const int*   src  = (const int*)d_in[19];
    const int*   dst  = (const int*)d_in[20];

    const int N = in_sizes[0] / D;
    const int E = in_sizes[1] / D;
    const size_t ND = (size_t)N * D;

    float* out   = (float*)d_out;
    float* h_out = out;
    float* e_out = out + ND;                  // holds he, then relu(he)
    float* p_out = out + ND + (size_t)E * D;

    // ws layout: 6*ND (P1,P2,P3) + ND (C1p) + E (alpha) floats +
    // (2N + E + 256) ints ~= 97 MB
    float*  ws    = (float*)d_ws;
    float2* P1    = (float2*)(ws);            // 2*ND floats
    float2* P2    = (float2*)(ws + 2 * ND);   // 2*ND floats
    float2* P3    = (float2*)(ws + 4 * ND);   // 2*ND floats
    float*  C1pA  = ws + 6 * ND;              // ND floats
    float*  alpha = ws + 7 * ND;              // E floats
    int*    cnt   = (int*)(ws + 7 * ND + E);  // N ints
    int*    offs  = cnt + N;                  // N ints
    int*    bucket= offs + N;                 // E ints
    int*    csum  = bucket + E;               // nchunk ints (<=256)

    const int nchunk = (N + 255) / 256;

    hipMemsetAsync(cnt, 0, (size_t)N * sizeof(int), stream);

    node_linears<<<(N + NT - 1) / NT, 256, 0, stream>>>(
        h, p, WK, bK, WV, bV, WB1, bB1, WB2, bB2, WC1, bC1, WC2, bC2,
        P1, P2, P3, C1pA, N);

    hist_kernel<<<(E + 255) / 256, 256, 0, stream>>>(dst, cnt, E);
    chunksum_kernel<<<nchunk, 256, 0, stream>>>(cnt, csum, N);
    scanchunk_kernel<<<1, 256, 0, stream>>>(csum, nchunk);
    offsets_kernel<<<nchunk, 256, 0, stream>>>(cnt, csum, offs, N);
    scatter_kernel<<<(E + 255) / 256, 256, 0, stream>>>(dst, offs, bucket, E);

    edge_compute<<<6400, 256, 0, stream>>>(
        e, src, dst, WB3, bB3, P1, P2, e_out, alpha, E);

    gather_finalize<<<(N + 3) / 4, 256, 0, stream>>>(
        bucket, offs, cnt, src, alpha, P3, C1pA, ln_g, ln_b,
        e_out, h_out, p_out, N);
}

// Round 8
// 1057.074 us; speedup vs baseline: 1.4312x; 1.4312x over previous
//
#include <hip/hip_runtime.h>
#include <math.h>

#define D 64
#define EPS 1e-12f
#define LN_EPS 1e-5f
#define NT 64    // nodes per block in node_linears
#define CHK 16   // bucket entries per wave-chunk in seg_edge

// bf16 round-to-nearest-even packing helpers
__device__ __forceinline__ unsigned int f2bf_bits(float x) {
    unsigned int u = __float_as_uint(x);
    return (u + 0x7fffu + ((u >> 16) & 1u)) >> 16;
}
__device__ __forceinline__ float bf_lo(unsigned int p) {  // low 16 bits -> float
    return __uint_as_float(p << 16);
}
__device__ __forceinline__ float bf_hi(unsigned int p) {  // high 16 bits -> float
    return __uint_as_float(p & 0xffff0000u);
}

// ---------------------------------------------------------------------------
// Kernel A: per-node linears, tile-parallel (structure verified R3-R6).
// Phase order: stage-x, WK, WB1/WB2, WV, WC1/WC2.
// WV stores vh into the (dead after WB) h-slot of xs so WC can pack
// P3u = {bf16(vh), bf16(C2p)} in a single write. C1p goes straight to the
// p_out region of d_out (finalize reads it back and overwrites with tanh).
//   P1[n*64+d] = {B1h, sigmaQ} f32x2  (gathered by src)
//   P2[n*64+d] = {B2h, sigmaK} f32x2  (gathered by dst, once per run)
//   P3u[n*64+d] = packed bf16 {vh, C2p} (gathered by src)
// ---------------------------------------------------------------------------
__global__ void __launch_bounds__(256, 2)
node_linears(const float* __restrict__ h, const float* __restrict__ p,
             const float* __restrict__ WK, const float* __restrict__ bK,
             const float* __restrict__ WV, const float* __restrict__ bV,
             const float* __restrict__ WB1, const float* __restrict__ bB1,
             const float* __restrict__ WB2, const float* __restrict__ bB2,
             const float* __restrict__ WC1, const float* __restrict__ bC1,
             const float* __restrict__ WC2, const float* __restrict__ bC2,
             float2* __restrict__ P1, float2* __restrict__ P2,
             unsigned int* __restrict__ P3u, float* __restrict__ C1pOut,
             int N)
{
    __shared__ float xs[NT * 128];    // [n][k], k<64 = h, k>=64 = p
    __shared__ float wsm[64 * 128];   // phase weight buffer, f4-swizzled

    const int t = threadIdx.x;
    const int lane = t & 63;
    const int wid = t >> 6;
    const int n0 = blockIdx.x * NT;

    float4* xs4 = (float4*)xs;
    float4* wsm4 = (float4*)wsm;

    {
        const float4* h4 = (const float4*)h;
        const float4* p4 = (const float4*)p;
        for (int i = t; i < NT * 32; i += 256) {
            int n = i >> 5, kq = i & 31;
            int ng = n0 + n;
            float4 v = make_float4(0.f, 0.f, 0.f, 0.f);
            if (ng < N) v = (kq < 16) ? h4[(size_t)ng * 16 + kq]
                                      : p4[(size_t)ng * 16 + (kq - 16)];
            xs4[n * 32 + kq] = v;
        }
    }
    __syncthreads();

#define STAGE_W128(W)                                                    \
    {                                                                    \
        const float4* w4 = (const float4*)(W);                           \
        for (int i = t; i < 64 * 32; i += 256) {                         \
            int d = i >> 5, j = i & 31;                                  \
            wsm4[d * 32 + (j ^ (d & 31))] = w4[i];                       \
        }                                                                \
    }                                                                    \
    __syncthreads();

#define LOAD_ROW128(wreg)                                                \
    _Pragma("unroll")                                                    \
    for (int j = 0; j < 32; ++j) wreg[j] = wsm4[lane * 32 + (j ^ (lane & 31))];

    // ---- WK phase: sigmaQ -> P1.y, sigmaK -> P2.y ----
    {
        STAGE_W128(WK);
        float4 w[32];
        LOAD_ROW128(w);
        float bk = bK[lane];
#pragma unroll 1
        for (int i = 0; i < 16; ++i) {
            int n = wid * 16 + i;
            const float4* xv = (const float4*)&xs[n * 128];
            float a0 = 0.f, a1 = 0.f, a2 = 0.f, a3 = 0.f;
#pragma unroll
            for (int j = 0; j < 32; j += 4) {
                float4 x0 = xv[j + 0], x1 = xv[j + 1], x2 = xv[j + 2], x3 = xv[j + 3];
                a0 += w[j+0].x*x0.x + w[j+0].y*x0.y + w[j+0].z*x0.z + w[j+0].w*x0.w;
                a1 += w[j+1].x*x1.x + w[j+1].y*x1.y + w[j+1].z*x1.z + w[j+1].w*x1.w;
                a2 += w[j+2].x*x2.x + w[j+2].y*x2.y + w[j+2].z*x2.z + w[j+2].w*x2.w;
                a3 += w[j+3].x*x3.x + w[j+3].y*x3.y + w[j+3].z*x3.z + w[j+3].w*x3.w;
            }
            float aq = bk + (a0 + a1) + (a2 + a3);
            int ng = n0 + n;
            if (ng < N) {
                size_t o = (size_t)ng * 64 + lane;
                P1[o].y = expf(tanhf(aq));
                P2[o].y = expf(1.f / (1.f + expf(-aq)));
            }
        }
        __syncthreads();
    }

#define STAGE_W64x2(WA, WB)                                              \
    {                                                                    \
        for (int i = t; i < 2048; i += 256) {                            \
            int m = i >> 10;                                             \
            int r = i & 1023;                                            \
            int d = r >> 4, j = r & 15;                                  \
            const float4* w4 = m ? (const float4*)(WB) : (const float4*)(WA); \
            wsm4[m * 1024 + d * 16 + (j ^ (d & 15))] = w4[r];            \
        }                                                                \
    }                                                                    \
    __syncthreads();

    // ---- WB1/WB2 phase (input h): B1h -> P1.x, B2h -> P2.x ----
    // (runs BEFORE WV so the xs h-slot is dead afterwards)
    {
        STAGE_W64x2(WB1, WB2);
        float4 w1[16], w2[16];
#pragma unroll
        for (int j = 0; j < 16; ++j) {
            w1[j] = wsm4[lane * 16 + (j ^ (lane & 15))];
            w2[j] = wsm4[1024 + lane * 16 + (j ^ (lane & 15))];
        }
        float b1 = bB1[lane], b2 = bB2[lane];
#pragma unroll 1
        for (int i = 0; i < 16; ++i) {
            int n = wid * 16 + i;
            const float4* xv = (const float4*)&xs[n * 128];
            float a0 = 0.f, a1 = 0.f, c0 = 0.f, c1 = 0.f;
#pragma unroll
            for (int j = 0; j < 16; j += 2) {
                float4 x0 = xv[j], x1 = xv[j + 1];
                a0 += w1[j].x*x0.x + w1[j].y*x0.y + w1[j].z*x0.z + w1[j].w*x0.w;
                a1 += w1[j+1].x*x1.x + w1[j+1].y*x1.y + w1[j+1].z*x1.z + w1[j+1].w*x1.w;
                c0 += w2[j].x*x0.x + w2[j].y*x0.y + w2[j].z*x0.z + w2[j].w*x0.w;
                c1 += w2[j+1].x*x1.x + w2[j+1].y*x1.y + w2[j+1].z*x1.z + w2[j+1].w*x1.w;
            }
            int ng = n0 + n;
            if (ng < N) {
                size_t o = (size_t)ng * 64 + lane;
                P1[o].x = b1 + a0 + a1;
                P2[o].x = b2 + c0 + c1;
            }
        }
        __syncthreads();
    }

    // ---- WV phase: vh -> xs h-slot (register->LDS stash, packed later) ----
    {
        STAGE_W128(WV);
        float4 w[32];
        LOAD_ROW128(w);
        float bv = bV[lane];
#pragma unroll 1
        for (int i = 0; i < 16; ++i) {
            int n = wid * 16 + i;
            const float4* xv = (const float4*)&xs[n * 128];
            float a0 = 0.f, a1 = 0.f, a2 = 0.f, a3 = 0.f;
#pragma unroll
            for (int j = 0; j < 32; j += 4) {
                float4 x0 = xv[j + 0], x1 = xv[j + 1], x2 = xv[j + 2], x3 = xv[j + 3];
                a0 += w[j+0].x*x0.x + w[j+0].y*x0.y + w[j+0].z*x0.z + w[j+0].w*x0.w;
                a1 += w[j+1].x*x1.x + w[j+1].y*x1.y + w[j+1].z*x1.z + w[j+1].w*x1.w;
                a2 += w[j+2].x*x2.x + w[j+2].y*x2.y + w[j+2].z*x2.z + w[j+2].w*x2.w;
                a3 += w[j+3].x*x3.x + w[j+3].y*x3.y + w[j+3].z*x3.z + w[j+3].w*x3.w;
            }
            float av = bv + (a0 + a1) + (a2 + a3);
            // all reads of row n precede this write in program order (lockstep)
            xs[n * 128 + lane] = av;
        }
        __syncthreads();
    }

    // ---- WC1/WC2 phase (input p): C1p -> C1pOut (=p_out), pack P3u ----
    {
        STAGE_W64x2(WC1, WC2);
        float4 w1[16], w2[16];
#pragma unroll
        for (int j = 0; j < 16; ++j) {
            w1[j] = wsm4[lane * 16 + (j ^ (lane & 15))];
            w2[j] = wsm4[1024 + lane * 16 + (j ^ (lane & 15))];
        }
        float b1 = bC1[lane], b2 = bC2[lane];
#pragma unroll 1
        for (int i = 0; i < 16; ++i) {
            int n = wid * 16 + i;
            const float4* xv = (const float4*)&xs[n * 128 + 64];
            float a0 = 0.f, a1 = 0.f, c0 = 0.f, c1 = 0.f;
#pragma unroll
            for (int j = 0; j < 16; j += 2) {
                float4 x0 = xv[j], x1 = xv[j + 1];
                a0 += w1[j].x*x0.x + w1[j].y*x0.y + w1[j].z*x0.z + w1[j].w*x0.w;
                a1 += w1[j+1].x*x1.x + w1[j+1].y*x1.y + w1[j+1].z*x1.z + w1[j+1].w*x1.w;
                c0 += w2[j].x*x0.x + w2[j].y*x0.y + w2[j].z*x0.z + w2[j].w*x0.w;
                c1 += w2[j+1].x*x1.x + w2[j+1].y*x1.y + w2[j+1].z*x1.z + w2[j+1].w*x1.w;
            }
            int ng = n0 + n;
            if (ng < N) {
                size_t o = (size_t)ng * 64 + lane;
                C1pOut[o] = b1 + a0 + a1;                       // C1p -> p_out
                float c2 = b2 + c0 + c1;
                float vh = xs[n * 128 + lane];                  // stashed vh
                P3u[o] = f2bf_bits(vh) | (f2bf_bits(c2) << 16);
            }
        }
    }
}

// ---------------------------------------------------------------------------
// dst-bucketing pipeline (int atomics only; unchanged -- verified R4-R6).
// ---------------------------------------------------------------------------
__global__ void hist_kernel(const int* __restrict__ dst, int* __restrict__ cnt, int E) {
    int i = blockIdx.x * blockDim.x + threadIdx.x;
    if (i < E) atomicAdd(&cnt[dst[i]], 1);
}

__global__ void chunksum_kernel(const int* __restrict__ cnt, int* __restrict__ csum, int N) {
    __shared__ int sc[256];
    int t = threadIdx.x;
    int i = blockIdx.x * 256 + t;
    sc[t] = (i < N) ? cnt[i] : 0;
    __syncthreads();
    for (int off = 128; off > 0; off >>= 1) {
        if (t < off) sc[t] += sc[t + off];
        __syncthreads();
    }
    if (t == 0) csum[blockIdx.x] = sc[0];
}

__global__ void scanchunk_kernel(int* __restrict__ csum, int nch) {
    __shared__ int sc[256];
    int t = threadIdx.x;
    int v = (t < nch) ? csum[t] : 0;
    sc[t] = v;
    __syncthreads();
    for (int off = 1; off < 256; off <<= 1) {
        int y = (t >= off) ? sc[t - off] : 0;
        __syncthreads();
        sc[t] += y;
        __syncthreads();
    }
    if (t < nch) csum[t] = sc[t] - v;   // exclusive prefix
}

__global__ void offsets_kernel(const int* __restrict__ cnt, const int* __restrict__ csum,
                               int* __restrict__ offs, int N) {
    __shared__ int sc[256];
    int t = threadIdx.x;
    int i = blockIdx.x * 256 + t;
    int v = (i < N) ? cnt[i] : 0;
    sc[t] = v;
    __syncthreads();
    for (int off = 1; off < 256; off <<= 1) {
        int y = (t >= off) ? sc[t - off] : 0;
        __syncthreads();
        sc[t] += y;
        __syncthreads();
    }
    if (i < N) offs[i] = csum[blockIdx.x] + sc[t] - v;  // global exclusive prefix
}

__global__ void scatter_kernel(const int* __restrict__ dst, int* __restrict__ offs,
                               int* __restrict__ bucket, int E) {
    int i = blockIdx.x * blockDim.x + threadIdx.x;
    if (i < E) {
        int pos = atomicAdd(&offs[dst[i]], 1);
        bucket[pos] = i;
    }
}

// ---------------------------------------------------------------------------
// Kernel B: SINGLE segmented edge pass. Wave-per-chunk of CHK bucket entries
// (bucket is dst-sorted). lane = feature dim.
//  - P2[t] row loaded once per dst-run, not per edge
//  - per edge: P1[s] gather (f32x2), P3u[s] gather (bf16x2), e-row matvec
//    (depth-2 prefetch of next edge's ids+gathers), e_out written ONCE,
//    alpha butterfly, register accumulation of {Ssig, Sv, Sp}
//  - flush via unsafeAtomicAdd only at run/chunk boundaries (~100k flushes,
//    19M lane atomics -- 8x fewer than the R2 all-atomic design)
// ---------------------------------------------------------------------------
__global__ void __launch_bounds__(256, 4)
seg_edge(const int* __restrict__ bucket, const int* __restrict__ src,
         const int* __restrict__ dst, const float* __restrict__ e,
         const float* __restrict__ WB3, const float* __restrict__ bB3,
         const float2* __restrict__ P1, const float2* __restrict__ P2,
         const unsigned int* __restrict__ P3u,
         float* __restrict__ e_out, float* __restrict__ S_sig,
         float* __restrict__ S_v, float* __restrict__ S_p, int E)
{
    const int lane = threadIdx.x & 63;
    const int wid = threadIdx.x >> 6;
    const int chunk = blockIdx.x * 4 + wid;
    const int nch = (E + CHK - 1) / CHK;
    if (chunk >= nch) return;
    const int k0 = chunk * CHK;
    const int k1 = (k0 + CHK < E) ? k0 + CHK : E;

    float4 wb3[16];
    const float4* w4 = (const float4*)(WB3 + (size_t)lane * D);
#pragma unroll
    for (int j = 0; j < 16; ++j) wb3[j] = w4[j];
    const float bb3 = bB3[lane];

    int eid = __builtin_amdgcn_readfirstlane(bucket[k0]);
    int s   = __builtin_amdgcn_readfirstlane(src[eid]);
    int t   = __builtin_amdgcn_readfirstlane(dst[eid]);
    float2 p1 = P1[(size_t)s * D + lane];
    unsigned int p3 = P3u[(size_t)s * D + lane];
    float2 b2 = P2[(size_t)t * D + lane];

    float asig = 0.f, av = 0.f, ap = 0.f;

    for (int k = k0; k < k1; ++k) {
        const bool more = (k + 1 < k1);
        int eidn = eid, sn = s, tn = t;
        float2 p1n = p1;
        unsigned int p3n = p3;
        if (more) {
            eidn = __builtin_amdgcn_readfirstlane(bucket[k + 1]);
            sn   = __builtin_amdgcn_readfirstlane(src[eidn]);
            tn   = __builtin_amdgcn_readfirstlane(dst[eidn]);
            p1n  = P1[(size_t)sn * D + lane];
            p3n  = P3u[(size_t)sn * D + lane];
        }

        // e-row broadcast matvec for current edge
        const float4* er = (const float4*)(e + (size_t)eid * D);
        float b3 = bb3;
#pragma unroll
        for (int j = 0; j < 16; ++j) {
            float4 ev = er[j];
            b3 += ev.x*wb3[j].x + ev.y*wb3[j].y + ev.z*wb3[j].z + ev.w*wb3[j].w;
        }

        float he = p1.x + b2.x + b3;
        e_out[(size_t)eid * D + lane] = fmaxf(he, 0.f);
        float sg = 1.f / (1.f + expf(-he));

        float prod = p1.y * b2.y;
#pragma unroll
        for (int off = 32; off > 0; off >>= 1) prod += __shfl_xor(prod, off);

        asig += sg;
        av   += sg * prod * bf_lo(p3);
        ap   += sg * bf_hi(p3);

        const bool newt = more && (tn != t);
        if (newt || !more) {
            size_t to = (size_t)t * D + lane;
            unsafeAtomicAdd(&S_sig[to], asig);
            unsafeAtomicAdd(&S_v[to], av);
            unsafeAtomicAdd(&S_p[to], ap);
            asig = 0.f; av = 0.f; ap = 0.f;
        }
        if (newt) b2 = P2[(size_t)tn * D + lane];

        eid = eidn; s = sn; t = tn; p1 = p1n; p3 = p3n;
    }
}

// ---------------------------------------------------------------------------
// Kernel C: light finalize. wave-per-node, lane = feature dim.
// h_out arrives holding S_v, p_out holding C1p, S_sig/S_p in ws.
// ---------------------------------------------------------------------------
__global__ void __launch_bounds__(256, 4)
finalize(const float* __restrict__ S_sig, const float* __restrict__ S_p,
         const unsigned int* __restrict__ P3u,
         const float* __restrict__ ln_g, const float* __restrict__ ln_b,
         float* __restrict__ h_out, float* __restrict__ p_out, int N)
{
    const int lane = threadIdx.x & 63;
    const int wid = threadIdx.x >> 6;
    const int wpb = blockDim.x >> 6;
    const float lg = ln_g[lane], lb = ln_b[lane];

    for (int n = blockIdx.x * wpb + wid; n < N; n += gridDim.x * wpb) {
        size_t o = (size_t)n * D + lane;
        float denom = S_sig[o] + EPS;
        float vh = bf_lo(P3u[o]);
        float hv = vh + h_out[o] / denom;
        hv = fmaxf(hv, 0.f);
        float su = hv;
#pragma unroll
        for (int off = 32; off > 0; off >>= 1) su += __shfl_xor(su, off);
        float mu = su * (1.f / 64.f);
        float dv = hv - mu;
        float s2 = dv * dv;
#pragma unroll
        for (int off = 32; off > 0; off >>= 1) s2 += __shfl_xor(s2, off);
        float var = s2 * (1.f / 64.f);
        h_out[o] = dv * rsqrtf(var + LN_EPS) * lg + lb;

        float pv = p_out[o] + S_p[o] / denom;   // p_out holds C1p
        p_out[o] = tanhf(pv);
    }
}

extern "C" void kernel_launch(void* const* d_in, const int* in_sizes, int n_in,
                              void* d_out, int out_size, void* d_ws, size_t ws_size,
                              hipStream_t stream) {
    const float* h    = (const float*)d_in[0];
    const float* e    = (const float*)d_in[1];
    const float* p    = (const float*)d_in[2];
    const float* WK   = (const float*)d_in[3];
    const float* bK   = (const float*)d_in[4];
    const float* WV   = (const float*)d_in[5];
    const float* bV   = (const float*)d_in[6];
    const float* WB1  = (const float*)d_in[7];
    const float* bB1  = (const float*)d_in[8];
    const float* WB2  = (const float*)d_in[9];
    const float* bB2  = (const float*)d_in[10];
    const float* WB3  = (const float*)d_in[11];
    const float* bB3  = (const float*)d_in[12];
    const float* WC1  = (const float*)d_in[13];
    const float* bC1  = (const float*)d_in[14];
    const float* WC2  = (const float*)d_in[15];
    const float* bC2  = (const float*)d_in[16];
    const float* ln_g = (const float*)d_in[17];
    const float* ln_b = (const float*)d_in[18];
    const int*   src  = (const int*)d_in[19];
    const int*   dst  = (const int*)d_in[20];

    const int N = in_sizes[0] / D;
    const int E = in_sizes[1] / D;
    const size_t ND = (size_t)N * D;

    float* out   = (float*)d_out;
    float* h_out = out;                       // S_v accumulator, then h_out
    float* e_out = out + ND;
    float* p_out = out + ND + (size_t)E * D;  // C1p, then p_out

    // ws: P1 2ND + P2 2ND + S_sig ND + S_p ND (f32) + P3u ND (u32)
    //   + cnt N + offs N + bucket E + csum (int)  ~= 93 MB
    float*        ws    = (float*)d_ws;
    float2*       P1    = (float2*)(ws);              // 2*ND floats
    float2*       P2    = (float2*)(ws + 2 * ND);     // 2*ND floats
    float*        S_sig = ws + 4 * ND;                // ND floats
    float*        S_p   = ws + 5 * ND;                // ND floats
    unsigned int* P3u   = (unsigned int*)(ws + 6 * ND); // ND u32
    int*          cnt   = (int*)(ws + 7 * ND);        // N ints
    int*          offs  = cnt + N;                    // N ints
    int*          bucket= offs + N;                   // E ints
    int*          csum  = bucket + E;                 // nchunk ints (<=256)

    const int nchunk = (N + 255) / 256;

    hipMemsetAsync(cnt, 0, (size_t)N * sizeof(int), stream);
    hipMemsetAsync(h_out, 0, ND * sizeof(float), stream);
    hipMemsetAsync(S_sig, 0, ND * sizeof(float), stream);
    hipMemsetAsync(S_p, 0, ND * sizeof(float), stream);

    node_linears<<<(N + NT - 1) / NT, 256, 0, stream>>>(
        h, p, WK, bK, WV, bV, WB1, bB1, WB2, bB2, WC1, bC1, WC2, bC2,
        P1, P2, P3u, p_out, N);

    hist_kernel<<<(E + 255) / 256, 256, 0, stream>>>(dst, cnt, E);
    chunksum_kernel<<<nchunk, 256, 0, stream>>>(cnt, csum, N);
    scanchunk_kernel<<<1, 256, 0, stream>>>(csum, nchunk);
    offsets_kernel<<<nchunk, 256, 0, stream>>>(cnt, csum, offs, N);
    scatter_kernel<<<(E + 255) / 256, 256, 0, stream>>>(dst, offs, bucket, E);

    const int nseg = (E + CHK - 1) / CHK;           // 50000 chunks
    seg_edge<<<(nseg + 3) / 4, 256, 0, stream>>>(
        bucket, src, dst, e, WB3, bB3, P1, P2, P3u,
        e_out, S_sig, h_out, S_p, E);

    finalize<<<(N + 3) / 4, 256, 0, stream>>>(
        S_sig, S_p, P3u, ln_g, ln_b, h_out, p_out, N);
}

// Round 9
// 824.310 us; speedup vs baseline: 1.8353x; 1.2824x over previous
//
#include <hip/hip_runtime.h>
#include <math.h>

#define D 64
#define EPS 1e-12f
#define LN_EPS 1e-5f
#define NT 64    // nodes per block in node_linears

// bf16 round-to-nearest-even packing helpers
__device__ __forceinline__ unsigned int f2bf_bits(float x) {
    unsigned int u = __float_as_uint(x);
    return (u + 0x7fffu + ((u >> 16) & 1u)) >> 16;
}
__device__ __forceinline__ float bf_lo(unsigned int p) {  // low 16 bits -> float
    return __uint_as_float(p << 16);
}
__device__ __forceinline__ float bf_hi(unsigned int p) {  // high 16 bits -> float
    return __uint_as_float(p & 0xffff0000u);
}

// ---------------------------------------------------------------------------
// Kernel A: per-node linears, tile-parallel (verified R8, reused verbatim).
// Phase order: stage-x, WK, WB1/WB2, WV (stash vh in dead xs h-slot), WC1/WC2.
//   P1[n*64+d]  = {B1h, sigmaQ} f32x2   (gathered by src)
//   P2[n*64+d]  = {B2h, sigmaK} f32x2   (gathered by dst)
//   P3u[n*64+d] = packed bf16 {vh, C2p} (gathered by src; vh also epilogue)
//   C1p -> p_out region (read back in gather_finalize epilogue)
// ---------------------------------------------------------------------------
__global__ void __launch_bounds__(256, 2)
node_linears(const float* __restrict__ h, const float* __restrict__ p,
             const float* __restrict__ WK, const float* __restrict__ bK,
             const float* __restrict__ WV, const float* __restrict__ bV,
             const float* __restrict__ WB1, const float* __restrict__ bB1,
             const float* __restrict__ WB2, const float* __restrict__ bB2,
             const float* __restrict__ WC1, const float* __restrict__ bC1,
             const float* __restrict__ WC2, const float* __restrict__ bC2,
             float2* __restrict__ P1, float2* __restrict__ P2,
             unsigned int* __restrict__ P3u, float* __restrict__ C1pOut,
             int N)
{
    __shared__ float xs[NT * 128];    // [n][k], k<64 = h, k>=64 = p
    __shared__ float wsm[64 * 128];   // phase weight buffer, f4-swizzled

    const int t = threadIdx.x;
    const int lane = t & 63;
    const int wid = t >> 6;
    const int n0 = blockIdx.x * NT;

    float4* xs4 = (float4*)xs;
    float4* wsm4 = (float4*)wsm;

    {
        const float4* h4 = (const float4*)h;
        const float4* p4 = (const float4*)p;
        for (int i = t; i < NT * 32; i += 256) {
            int n = i >> 5, kq = i & 31;
            int ng = n0 + n;
            float4 v = make_float4(0.f, 0.f, 0.f, 0.f);
            if (ng < N) v = (kq < 16) ? h4[(size_t)ng * 16 + kq]
                                      : p4[(size_t)ng * 16 + (kq - 16)];
            xs4[n * 32 + kq] = v;
        }
    }
    __syncthreads();

#define STAGE_W128(W)                                                    \
    {                                                                    \
        const float4* w4 = (const float4*)(W);                           \
        for (int i = t; i < 64 * 32; i += 256) {                         \
            int d = i >> 5, j = i & 31;                                  \
            wsm4[d * 32 + (j ^ (d & 31))] = w4[i];                       \
        }                                                                \
    }                                                                    \
    __syncthreads();

#define LOAD_ROW128(wreg)                                                \
    _Pragma("unroll")                                                    \
    for (int j = 0; j < 32; ++j) wreg[j] = wsm4[lane * 32 + (j ^ (lane & 31))];

    // ---- WK phase: sigmaQ -> P1.y, sigmaK -> P2.y ----
    {
        STAGE_W128(WK);
        float4 w[32];
        LOAD_ROW128(w);
        float bk = bK[lane];
#pragma unroll 1
        for (int i = 0; i < 16; ++i) {
            int n = wid * 16 + i;
            const float4* xv = (const float4*)&xs[n * 128];
            float a0 = 0.f, a1 = 0.f, a2 = 0.f, a3 = 0.f;
#pragma unroll
            for (int j = 0; j < 32; j += 4) {
                float4 x0 = xv[j + 0], x1 = xv[j + 1], x2 = xv[j + 2], x3 = xv[j + 3];
                a0 += w[j+0].x*x0.x + w[j+0].y*x0.y + w[j+0].z*x0.z + w[j+0].w*x0.w;
                a1 += w[j+1].x*x1.x + w[j+1].y*x1.y + w[j+1].z*x1.z + w[j+1].w*x1.w;
                a2 += w[j+2].x*x2.x + w[j+2].y*x2.y + w[j+2].z*x2.z + w[j+2].w*x2.w;
                a3 += w[j+3].x*x3.x + w[j+3].y*x3.y + w[j+3].z*x3.z + w[j+3].w*x3.w;
            }
            float aq = bk + (a0 + a1) + (a2 + a3);
            int ng = n0 + n;
            if (ng < N) {
                size_t o = (size_t)ng * 64 + lane;
                P1[o].y = expf(tanhf(aq));
                P2[o].y = expf(1.f / (1.f + expf(-aq)));
            }
        }
        __syncthreads();
    }

#define STAGE_W64x2(WA, WB)                                              \
    {                                                                    \
        for (int i = t; i < 2048; i += 256) {                            \
            int m = i >> 10;                                             \
            int r = i & 1023;                                            \
            int d = r >> 4, j = r & 15;                                  \
            const float4* w4 = m ? (const float4*)(WB) : (const float4*)(WA); \
            wsm4[m * 1024 + d * 16 + (j ^ (d & 15))] = w4[r];            \
        }                                                                \
    }                                                                    \
    __syncthreads();

    // ---- WB1/WB2 phase (input h): B1h -> P1.x, B2h -> P2.x ----
    {
        STAGE_W64x2(WB1, WB2);
        float4 w1[16], w2[16];
#pragma unroll
        for (int j = 0; j < 16; ++j) {
            w1[j] = wsm4[lane * 16 + (j ^ (lane & 15))];
            w2[j] = wsm4[1024 + lane * 16 + (j ^ (lane & 15))];
        }
        float b1 = bB1[lane], b2 = bB2[lane];
#pragma unroll 1
        for (int i = 0; i < 16; ++i) {
            int n = wid * 16 + i;
            const float4* xv = (const float4*)&xs[n * 128];
            float a0 = 0.f, a1 = 0.f, c0 = 0.f, c1 = 0.f;
#pragma unroll
            for (int j = 0; j < 16; j += 2) {
                float4 x0 = xv[j], x1 = xv[j + 1];
                a0 += w1[j].x*x0.x + w1[j].y*x0.y + w1[j].z*x0.z + w1[j].w*x0.w;
                a1 += w1[j+1].x*x1.x + w1[j+1].y*x1.y + w1[j+1].z*x1.z + w1[j+1].w*x1.w;
                c0 += w2[j].x*x0.x + w2[j].y*x0.y + w2[j].z*x0.z + w2[j].w*x0.w;
                c1 += w2[j+1].x*x1.x + w2[j+1].y*x1.y + w2[j+1].z*x1.z + w2[j+1].w*x1.w;
            }
            int ng = n0 + n;
            if (ng < N) {
                size_t o = (size_t)ng * 64 + lane;
                P1[o].x = b1 + a0 + a1;
                P2[o].x = b2 + c0 + c1;
            }
        }
        __syncthreads();
    }

    // ---- WV phase: vh -> xs h-slot (dead after WB; lockstep-safe) ----
    {
        STAGE_W128(WV);
        float4 w[32];
        LOAD_ROW128(w);
        float bv = bV[lane];
#pragma unroll 1
        for (int i = 0; i < 16; ++i) {
            int n = wid * 16 + i;
            const float4* xv = (const float4*)&xs[n * 128];
            float a0 = 0.f, a1 = 0.f, a2 = 0.f, a3 = 0.f;
#pragma unroll
            for (int j = 0; j < 32; j += 4) {
                float4 x0 = xv[j + 0], x1 = xv[j + 1], x2 = xv[j + 2], x3 = xv[j + 3];
                a0 += w[j+0].x*x0.x + w[j+0].y*x0.y + w[j+0].z*x0.z + w[j+0].w*x0.w;
                a1 += w[j+1].x*x1.x + w[j+1].y*x1.y + w[j+1].z*x1.z + w[j+1].w*x1.w;
                a2 += w[j+2].x*x2.x + w[j+2].y*x2.y + w[j+2].z*x2.z + w[j+2].w*x2.w;
                a3 += w[j+3].x*x3.x + w[j+3].y*x3.y + w[j+3].z*x3.z + w[j+3].w*x3.w;
            }
            float av = bv + (a0 + a1) + (a2 + a3);
            xs[n * 128 + lane] = av;
        }
        __syncthreads();
    }

    // ---- WC1/WC2 phase (input p): C1p -> p_out region, pack P3u ----
    {
        STAGE_W64x2(WC1, WC2);
        float4 w1[16], w2[16];
#pragma unroll
        for (int j = 0; j < 16; ++j) {
            w1[j] = wsm4[lane * 16 + (j ^ (lane & 15))];
            w2[j] = wsm4[1024 + lane * 16 + (j ^ (lane & 15))];
        }
        float b1 = bC1[lane], b2 = bC2[lane];
#pragma unroll 1
        for (int i = 0; i < 16; ++i) {
            int n = wid * 16 + i;
            const float4* xv = (const float4*)&xs[n * 128 + 64];
            float a0 = 0.f, a1 = 0.f, c0 = 0.f, c1 = 0.f;
#pragma unroll
            for (int j = 0; j < 16; j += 2) {
                float4 x0 = xv[j], x1 = xv[j + 1];
                a0 += w1[j].x*x0.x + w1[j].y*x0.y + w1[j].z*x0.z + w1[j].w*x0.w;
                a1 += w1[j+1].x*x1.x + w1[j+1].y*x1.y + w1[j+1].z*x1.z + w1[j+1].w*x1.w;
                c0 += w2[j].x*x0.x + w2[j].y*x0.y + w2[j].z*x0.z + w2[j].w*x0.w;
                c1 += w2[j+1].x*x1.x + w2[j+1].y*x1.y + w2[j+1].z*x1.z + w2[j+1].w*x1.w;
            }
            int ng = n0 + n;
            if (ng < N) {
                size_t o = (size_t)ng * 64 + lane;
                C1pOut[o] = b1 + a0 + a1;
                float c2 = b2 + c0 + c1;
                float vh = xs[n * 128 + lane];
                P3u[o] = f2bf_bits(vh) | (f2bf_bits(c2) << 16);
            }
        }
    }
}

// ---------------------------------------------------------------------------
// dst-bucketing pipeline (int atomics only; verified R4-R8).
// ---------------------------------------------------------------------------
__global__ void hist_kernel(const int* __restrict__ dst, int* __restrict__ cnt, int E) {
    int i = blockIdx.x * blockDim.x + threadIdx.x;
    if (i < E) atomicAdd(&cnt[dst[i]], 1);
}

__global__ void chunksum_kernel(const int* __restrict__ cnt, int* __restrict__ csum, int N) {
    __shared__ int sc[256];
    int t = threadIdx.x;
    int i = blockIdx.x * 256 + t;
    sc[t] = (i < N) ? cnt[i] : 0;
    __syncthreads();
    for (int off = 128; off > 0; off >>= 1) {
        if (t < off) sc[t] += sc[t + off];
        __syncthreads();
    }
    if (t == 0) csum[blockIdx.x] = sc[0];
}

__global__ void scanchunk_kernel(int* __restrict__ csum, int nch) {
    __shared__ int sc[256];
    int t = threadIdx.x;
    int v = (t < nch) ? csum[t] : 0;
    sc[t] = v;
    __syncthreads();
    for (int off = 1; off < 256; off <<= 1) {
        int y = (t >= off) ? sc[t - off] : 0;
        __syncthreads();
        sc[t] += y;
        __syncthreads();
    }
    if (t < nch) csum[t] = sc[t] - v;   // exclusive prefix
}

__global__ void offsets_kernel(const int* __restrict__ cnt, const int* __restrict__ csum,
                               int* __restrict__ offs, int N) {
    __shared__ int sc[256];
    int t = threadIdx.x;
    int i = blockIdx.x * 256 + t;
    int v = (i < N) ? cnt[i] : 0;
    sc[t] = v;
    __syncthreads();
    for (int off = 1; off < 256; off <<= 1) {
        int y = (t >= off) ? sc[t - off] : 0;
        __syncthreads();
        sc[t] += y;
        __syncthreads();
    }
    if (i < N) offs[i] = csum[blockIdx.x] + sc[t] - v;  // global exclusive prefix
}

__global__ void scatter_kernel(const int* __restrict__ dst, int* __restrict__ offs,
                               int* __restrict__ bucket, int E) {
    int i = blockIdx.x * blockDim.x + threadIdx.x;
    if (i < E) {
        int pos = atomicAdd(&offs[dst[i]], 1);
        bucket[pos] = i;
    }
}

// ---------------------------------------------------------------------------
// Kernel B: edge compute, wave-per-edge-quad (ILP=4). lane = feature dim.
// 4 independent edges in flight per iteration; e-rows stay sequential
// (streaming). __launch_bounds__(256,3): VGPR cap ~168 so wb3[64] + 4-edge
// state stays register-resident (NO spill -- R7 lesson).
// Writes pre-activation he into the e_out region and alpha[E]. No atomics.
// ---------------------------------------------------------------------------
__global__ void __launch_bounds__(256, 3)
edge_compute(const float* __restrict__ e, const int* __restrict__ src,
             const int* __restrict__ dst,
             const float* __restrict__ WB3, const float* __restrict__ bB3,
             const float2* __restrict__ P1, const float2* __restrict__ P2,
             float* __restrict__ he_out, float* __restrict__ alpha, int E)
{
    const int lane = threadIdx.x & 63;
    const int wid = __builtin_amdgcn_readfirstlane((int)(threadIdx.x >> 6));
    const int wpb = blockDim.x >> 6;
    const int gw = blockIdx.x * wpb + wid;
    const int nw = gridDim.x * wpb;

    float4 wb3[16];
    const float4* w4 = (const float4*)(WB3 + (size_t)lane * D);
#pragma unroll
    for (int j = 0; j < 16; ++j) wb3[j] = w4[j];
    const float bb3 = bB3[lane];

    for (int ed = gw * 4; ed < E; ed += nw * 4) {
        int id[4], s[4], t[4];
#pragma unroll
        for (int i = 0; i < 4; ++i) {
            id[i] = (ed + i < E) ? ed + i : E - 1;
            s[i] = src[id[i]];
            t[i] = dst[id[i]];
        }
        float2 a[4], b[4];
#pragma unroll
        for (int i = 0; i < 4; ++i) {
            a[i] = P1[(size_t)s[i] * D + lane];   // {B1h, sigmaQ}
            b[i] = P2[(size_t)t[i] * D + lane];   // {B2h, sigmaK}
        }
        float hb[4];
#pragma unroll
        for (int i = 0; i < 4; ++i) hb[i] = bb3;
#pragma unroll
        for (int j = 0; j < 16; ++j) {
#pragma unroll
            for (int i = 0; i < 4; ++i) {
                float4 ev = ((const float4*)(e + (size_t)id[i] * D))[j];
                hb[i] += ev.x*wb3[j].x + ev.y*wb3[j].y + ev.z*wb3[j].z + ev.w*wb3[j].w;
            }
        }
        float pr[4];
#pragma unroll
        for (int i = 0; i < 4; ++i) {
            float he = a[i].x + b[i].x + hb[i];
            if (ed + i < E) he_out[(size_t)(ed + i) * D + lane] = he;
            pr[i] = a[i].y * b[i].y;
        }
#pragma unroll
        for (int off = 32; off > 0; off >>= 1) {
#pragma unroll
            for (int i = 0; i < 4; ++i) pr[i] += __shfl_xor(pr[i], off);
        }
        if (lane == 0) {
#pragma unroll
            for (int i = 0; i < 4; ++i)
                if (ed + i < E) alpha[ed + i] = pr[i];
        }
    }
}

// ---------------------------------------------------------------------------
// Kernel C: gather + finalize, wave-per-node, ILP=4 on the bucket walk.
// Reads he rows, overwrites with relu(he) in place (e_out), accumulates
// S_sig/S_v/S_p in registers (P3u bf16 gather), then fused epilogue.
// p_out region arrives holding C1p.
// ---------------------------------------------------------------------------
__global__ void __launch_bounds__(256, 4)
gather_finalize(const int* __restrict__ bucket, const int* __restrict__ offs_end,
                const int* __restrict__ cnt, const int* __restrict__ src,
                const float* __restrict__ alpha,
                const unsigned int* __restrict__ P3u,
                const float* __restrict__ ln_g, const float* __restrict__ ln_b,
                float* __restrict__ he_eout, float* __restrict__ h_out,
                float* __restrict__ p_out, int N)
{
    const int lane = threadIdx.x & 63;
    const int wid = threadIdx.x >> 6;
    const int wpb = blockDim.x >> 6;
    const float lg = ln_g[lane], lb = ln_b[lane];

    for (int n = blockIdx.x * wpb + wid; n < N; n += gridDim.x * wpb) {
        const int end = offs_end[n];
        const int deg = cnt[n];
        const int start = end - deg;
        const size_t o = (size_t)n * D + lane;

        float asig = 0.f, av = 0.f, ap = 0.f;

        int k = start;
        for (; k + 3 < end; k += 4) {
            int eid[4], s[4];
#pragma unroll
            for (int i = 0; i < 4; ++i)
                eid[i] = __builtin_amdgcn_readfirstlane(bucket[k + i]);
#pragma unroll
            for (int i = 0; i < 4; ++i)
                s[i] = __builtin_amdgcn_readfirstlane(src[eid[i]]);
            float al[4], he[4];
            unsigned int p3[4];
#pragma unroll
            for (int i = 0; i < 4; ++i) {
                al[i] = alpha[eid[i]];
                he[i] = he_eout[(size_t)eid[i] * D + lane];
                p3[i] = P3u[(size_t)s[i] * D + lane];
            }
#pragma unroll
            for (int i = 0; i < 4; ++i) {
                he_eout[(size_t)eid[i] * D + lane] = fmaxf(he[i], 0.f);
                float sg = 1.f / (1.f + expf(-he[i]));
                asig += sg;
                av   += sg * al[i] * bf_lo(p3[i]);
                ap   += sg * bf_hi(p3[i]);
            }
        }
        for (; k < end; ++k) {
            int e0 = __builtin_amdgcn_readfirstlane(bucket[k]);
            int s0 = __builtin_amdgcn_readfirstlane(src[e0]);
            float al0 = alpha[e0];
            size_t eo0 = (size_t)e0 * D + lane;
            float he0 = he_eout[eo0];
            unsigned int p30 = P3u[(size_t)s0 * D + lane];
            he_eout[eo0] = fmaxf(he0, 0.f);
            float sg0 = 1.f / (1.f + expf(-he0));
            asig += sg0;
            av   += sg0 * al0 * bf_lo(p30);
            ap   += sg0 * bf_hi(p30);
        }

        // fused epilogue
        float denom = asig + EPS;
        float vh = bf_lo(P3u[o]);
        float hv = vh + av / denom;
        hv = fmaxf(hv, 0.f);
        float su = hv;
#pragma unroll
        for (int off = 32; off > 0; off >>= 1) su += __shfl_xor(su, off);
        float mu = su * (1.f / 64.f);
        float dv = hv - mu;
        float s2 = dv * dv;
#pragma unroll
        for (int off = 32; off > 0; off >>= 1) s2 += __shfl_xor(s2, off);
        float var = s2 * (1.f / 64.f);
        h_out[o] = dv * rsqrtf(var + LN_EPS) * lg + lb;

        float pv = p_out[o] + ap / denom;   // p_out holds C1p
        p_out[o] = tanhf(pv);
    }
}

extern "C" void kernel_launch(void* const* d_in, const int* in_sizes, int n_in,
                              void* d_out, int out_size, void* d_ws, size_t ws_size,
                              hipStream_t stream) {
    const float* h    = (const float*)d_in[0];
    const float* e    = (const float*)d_in[1];
    const float* p    = (const float*)d_in[2];
    const float* WK   = (const float*)d_in[3];
    const float* bK   = (const float*)d_in[4];
    const float* WV   = (const float*)d_in[5];
    const float* bV   = (const float*)d_in[6];
    const float* WB1  = (const float*)d_in[7];
    const float* bB1  = (const float*)d_in[8];
    const float* WB2  = (const float*)d_in[9];
    const float* bB2  = (const float*)d_in[10];
    const float* WB3  = (const float*)d_in[11];
    const float* bB3  = (const float*)d_in[12];
    const float* WC1  = (const float*)d_in[13];
    const float* bC1  = (const float*)d_in[14];
    const float* WC2  = (const float*)d_in[15];
    const float* bC2  = (const float*)d_in[16];
    const float* ln_g = (const float*)d_in[17];
    const float* ln_b = (const float*)d_in[18];
    const int*   src  = (const int*)d_in[19];
    const int*   dst  = (const int*)d_in[20];

    const int N = in_sizes[0] / D;
    const int E = in_sizes[1] / D;
    const size_t ND = (size_t)N * D;

    float* out   = (float*)d_out;
    float* h_out = out;
    float* e_out = out + ND;                  // holds he, then relu(he)
    float* p_out = out + ND + (size_t)E * D;  // C1p, then tanh(...)

    // ws: P1 2ND + P2 2ND (f32) + P3u ND (u32) + alpha E (f32)
    //   + cnt N + offs N + bucket E + csum (int)  ~= 74 MB
    float*        ws    = (float*)d_ws;
    float2*       P1    = (float2*)(ws);                // 2*ND floats
    float2*       P2    = (float2*)(ws + 2 * ND);       // 2*ND floats
    unsigned int* P3u   = (unsigned int*)(ws + 4 * ND); // ND u32
    float*        alpha = ws + 5 * ND;                  // E floats
    int*          cnt   = (int*)(ws + 5 * ND + E);      // N ints
    int*          offs  = cnt + N;                      // N ints
    int*          bucket= offs + N;                     // E ints
    int*          csum  = bucket + E;                   // nchunk ints (<=256)

    const int nchunk = (N + 255) / 256;

    hipMemsetAsync(cnt, 0, (size_t)N * sizeof(int), stream);

    node_linears<<<(N + NT - 1) / NT, 256, 0, stream>>>(
        h, p, WK, bK, WV, bV, WB1, bB1, WB2, bB2, WC1, bC1, WC2, bC2,
        P1, P2, P3u, p_out, N);

    hist_kernel<<<(E + 255) / 256, 256, 0, stream>>>(dst, cnt, E);
    chunksum_kernel<<<nchunk, 256, 0, stream>>>(cnt, csum, N);
    scanchunk_kernel<<<1, 256, 0, stream>>>(csum, nchunk);
    offsets_kernel<<<nchunk, 256, 0, stream>>>(cnt, csum, offs, N);
    scatter_kernel<<<(E + 255) / 256, 256, 0, stream>>>(dst, offs, bucket, E);

    edge_compute<<<3200, 256, 0, stream>>>(
        e, src, dst, WB3, bB3, P1, P2, e_out, alpha, E);

    gather_finalize<<<(N + 3) / 4, 256, 0, stream>>>(
        bucket, offs, cnt, src, alpha, P3u, ln_g, ln_b,
        e_out, h_out, p_out, N);
}

// Round 10
// 721.435 us; speedup vs baseline: 2.0970x; 1.1426x over previous
//
#include <hip/hip_runtime.h>
#include <math.h>

#define D 64
#define EPS 1e-12f
#define LN_EPS 1e-5f
#define NT 64    // nodes per block in node_linears

// bf16 round-to-nearest-even packing helpers
__device__ __forceinline__ unsigned int f2bf_bits(float x) {
    unsigned int u = __float_as_uint(x);
    return (u + 0x7fffu + ((u >> 16) & 1u)) >> 16;
}
__device__ __forceinline__ float bf_lo(unsigned int p) {  // low 16 bits -> float
    return __uint_as_float(p << 16);
}
__device__ __forceinline__ float bf_hi(unsigned int p) {  // high 16 bits -> float
    return __uint_as_float(p & 0xffff0000u);
}

// ---------------------------------------------------------------------------
// Kernel A: per-node linears, tile-parallel (verified R8/R9, verbatim).
//   P1[n*64+d]  = {B1h, sigmaQ} f32x2   (gathered by src)
//   P2[n*64+d]  = {B2h, sigmaK} f32x2   (loaded once per node, dst side)
//   P3u[n*64+d] = packed bf16 {vh, C2p} (gathered by src; vh also epilogue)
//   C1p -> p_out region (read back in epilogue)
// ---------------------------------------------------------------------------
__global__ void __launch_bounds__(256, 2)
node_linears(const float* __restrict__ h, const float* __restrict__ p,
             const float* __restrict__ WK, const float* __restrict__ bK,
             const float* __restrict__ WV, const float* __restrict__ bV,
             const float* __restrict__ WB1, const float* __restrict__ bB1,
             const float* __restrict__ WB2, const float* __restrict__ bB2,
             const float* __restrict__ WC1, const float* __restrict__ bC1,
             const float* __restrict__ WC2, const float* __restrict__ bC2,
             float2* __restrict__ P1, float2* __restrict__ P2,
             unsigned int* __restrict__ P3u, float* __restrict__ C1pOut,
             int N)
{
    __shared__ float xs[NT * 128];    // [n][k], k<64 = h, k>=64 = p
    __shared__ float wsm[64 * 128];   // phase weight buffer, f4-swizzled

    const int t = threadIdx.x;
    const int lane = t & 63;
    const int wid = t >> 6;
    const int n0 = blockIdx.x * NT;

    float4* xs4 = (float4*)xs;
    float4* wsm4 = (float4*)wsm;

    {
        const float4* h4 = (const float4*)h;
        const float4* p4 = (const float4*)p;
        for (int i = t; i < NT * 32; i += 256) {
            int n = i >> 5, kq = i & 31;
            int ng = n0 + n;
            float4 v = make_float4(0.f, 0.f, 0.f, 0.f);
            if (ng < N) v = (kq < 16) ? h4[(size_t)ng * 16 + kq]
                                      : p4[(size_t)ng * 16 + (kq - 16)];
            xs4[n * 32 + kq] = v;
        }
    }
    __syncthreads();

#define STAGE_W128(W)                                                    \
    {                                                                    \
        const float4* w4 = (const float4*)(W);                           \
        for (int i = t; i < 64 * 32; i += 256) {                         \
            int d = i >> 5, j = i & 31;                                  \
            wsm4[d * 32 + (j ^ (d & 31))] = w4[i];                       \
        }                                                                \
    }                                                                    \
    __syncthreads();

#define LOAD_ROW128(wreg)                                                \
    _Pragma("unroll")                                                    \
    for (int j = 0; j < 32; ++j) wreg[j] = wsm4[lane * 32 + (j ^ (lane & 31))];

    // ---- WK phase: sigmaQ -> P1.y, sigmaK -> P2.y ----
    {
        STAGE_W128(WK);
        float4 w[32];
        LOAD_ROW128(w);
        float bk = bK[lane];
#pragma unroll 1
        for (int i = 0; i < 16; ++i) {
            int n = wid * 16 + i;
            const float4* xv = (const float4*)&xs[n * 128];
            float a0 = 0.f, a1 = 0.f, a2 = 0.f, a3 = 0.f;
#pragma unroll
            for (int j = 0; j < 32; j += 4) {
                float4 x0 = xv[j + 0], x1 = xv[j + 1], x2 = xv[j + 2], x3 = xv[j + 3];
                a0 += w[j+0].x*x0.x + w[j+0].y*x0.y + w[j+0].z*x0.z + w[j+0].w*x0.w;
                a1 += w[j+1].x*x1.x + w[j+1].y*x1.y + w[j+1].z*x1.z + w[j+1].w*x1.w;
                a2 += w[j+2].x*x2.x + w[j+2].y*x2.y + w[j+2].z*x2.z + w[j+2].w*x2.w;
                a3 += w[j+3].x*x3.x + w[j+3].y*x3.y + w[j+3].z*x3.z + w[j+3].w*x3.w;
            }
            float aq = bk + (a0 + a1) + (a2 + a3);
            int ng = n0 + n;
            if (ng < N) {
                size_t o = (size_t)ng * 64 + lane;
                P1[o].y = expf(tanhf(aq));
                P2[o].y = expf(1.f / (1.f + expf(-aq)));
            }
        }
        __syncthreads();
    }

#define STAGE_W64x2(WA, WB)                                              \
    {                                                                    \
        for (int i = t; i < 2048; i += 256) {                            \
            int m = i >> 10;                                             \
            int r = i & 1023;                                            \
            int d = r >> 4, j = r & 15;                                  \
            const float4* w4 = m ? (const float4*)(WB) : (const float4*)(WA); \
            wsm4[m * 1024 + d * 16 + (j ^ (d & 15))] = w4[r];            \
        }                                                                \
    }                                                                    \
    __syncthreads();

    // ---- WB1/WB2 phase (input h): B1h -> P1.x, B2h -> P2.x ----
    {
        STAGE_W64x2(WB1, WB2);
        float4 w1[16], w2[16];
#pragma unroll
        for (int j = 0; j < 16; ++j) {
            w1[j] = wsm4[lane * 16 + (j ^ (lane & 15))];
            w2[j] = wsm4[1024 + lane * 16 + (j ^ (lane & 15))];
        }
        float b1 = bB1[lane], b2 = bB2[lane];
#pragma unroll 1
        for (int i = 0; i < 16; ++i) {
            int n = wid * 16 + i;
            const float4* xv = (const float4*)&xs[n * 128];
            float a0 = 0.f, a1 = 0.f, c0 = 0.f, c1 = 0.f;
#pragma unroll
            for (int j = 0; j < 16; j += 2) {
                float4 x0 = xv[j], x1 = xv[j + 1];
                a0 += w1[j].x*x0.x + w1[j].y*x0.y + w1[j].z*x0.z + w1[j].w*x0.w;
                a1 += w1[j+1].x*x1.x + w1[j+1].y*x1.y + w1[j+1].z*x1.z + w1[j+1].w*x1.w;
                c0 += w2[j].x*x0.x + w2[j].y*x0.y + w2[j].z*x0.z + w2[j].w*x0.w;
                c1 += w2[j+1].x*x1.x + w2[j+1].y*x1.y + w2[j+1].z*x1.z + w2[j+1].w*x1.w;
            }
            int ng = n0 + n;
            if (ng < N) {
                size_t o = (size_t)ng * 64 + lane;
                P1[o].x = b1 + a0 + a1;
                P2[o].x = b2 + c0 + c1;
            }
        }
        __syncthreads();
    }

    // ---- WV phase: vh -> xs h-slot (dead after WB; lockstep-safe) ----
    {
        STAGE_W128(WV);
        float4 w[32];
        LOAD_ROW128(w);
        float bv = bV[lane];
#pragma unroll 1
        for (int i = 0; i < 16; ++i) {
            int n = wid * 16 + i;
            const float4* xv = (const float4*)&xs[n * 128];
            float a0 = 0.f, a1 = 0.f, a2 = 0.f, a3 = 0.f;
#pragma unroll
            for (int j = 0; j < 32; j += 4) {
                float4 x0 = xv[j + 0], x1 = xv[j + 1], x2 = xv[j + 2], x3 = xv[j + 3];
                a0 += w[j+0].x*x0.x + w[j+0].y*x0.y + w[j+0].z*x0.z + w[j+0].w*x0.w;
                a1 += w[j+1].x*x1.x + w[j+1].y*x1.y + w[j+1].z*x1.z + w[j+1].w*x1.w;
                a2 += w[j+2].x*x2.x + w[j+2].y*x2.y + w[j+2].z*x2.z + w[j+2].w*x2.w;
                a3 += w[j+3].x*x3.x + w[j+3].y*x3.y + w[j+3].z*x3.z + w[j+3].w*x3.w;
            }
            float av = bv + (a0 + a1) + (a2 + a3);
            xs[n * 128 + lane] = av;
        }
        __syncthreads();
    }

    // ---- WC1/WC2 phase (input p): C1p -> p_out region, pack P3u ----
    {
        STAGE_W64x2(WC1, WC2);
        float4 w1[16], w2[16];
#pragma unroll
        for (int j = 0; j < 16; ++j) {
            w1[j] = wsm4[lane * 16 + (j ^ (lane & 15))];
            w2[j] = wsm4[1024 + lane * 16 + (j ^ (lane & 15))];
        }
        float b1 = bC1[lane], b2 = bC2[lane];
#pragma unroll 1
        for (int i = 0; i < 16; ++i) {
            int n = wid * 16 + i;
            const float4* xv = (const float4*)&xs[n * 128 + 64];
            float a0 = 0.f, a1 = 0.f, c0 = 0.f, c1 = 0.f;
#pragma unroll
            for (int j = 0; j < 16; j += 2) {
                float4 x0 = xv[j], x1 = xv[j + 1];
                a0 += w1[j].x*x0.x + w1[j].y*x0.y + w1[j].z*x0.z + w1[j].w*x0.w;
                a1 += w1[j+1].x*x1.x + w1[j+1].y*x1.y + w1[j+1].z*x1.z + w1[j+1].w*x1.w;
                c0 += w2[j].x*x0.x + w2[j].y*x0.y + w2[j].z*x0.z + w2[j].w*x0.w;
                c1 += w2[j+1].x*x1.x + w2[j+1].y*x1.y + w2[j+1].z*x1.z + w2[j+1].w*x1.w;
            }
            int ng = n0 + n;
            if (ng < N) {
                size_t o = (size_t)ng * 64 + lane;
                C1pOut[o] = b1 + a0 + a1;
                float c2 = b2 + c0 + c1;
                float vh = xs[n * 128 + lane];
                P3u[o] = f2bf_bits(vh) | (f2bf_bits(c2) << 16);
            }
        }
    }
}

// ---------------------------------------------------------------------------
// dst-bucketing pipeline (int atomics only; verified R4-R9).
// ---------------------------------------------------------------------------
__global__ void hist_kernel(const int* __restrict__ dst, int* __restrict__ cnt, int E) {
    int i = blockIdx.x * blockDim.x + threadIdx.x;
    if (i < E) atomicAdd(&cnt[dst[i]], 1);
}

__global__ void chunksum_kernel(const int* __restrict__ cnt, int* __restrict__ csum, int N) {
    __shared__ int sc[256];
    int t = threadIdx.x;
    int i = blockIdx.x * 256 + t;
    sc[t] = (i < N) ? cnt[i] : 0;
    __syncthreads();
    for (int off = 128; off > 0; off >>= 1) {
        if (t < off) sc[t] += sc[t + off];
        __syncthreads();
    }
    if (t == 0) csum[blockIdx.x] = sc[0];
}

__global__ void scanchunk_kernel(int* __restrict__ csum, int nch) {
    __shared__ int sc[256];
    int t = threadIdx.x;
    int v = (t < nch) ? csum[t] : 0;
    sc[t] = v;
    __syncthreads();
    for (int off = 1; off < 256; off <<= 1) {
        int y = (t >= off) ? sc[t - off] : 0;
        __syncthreads();
        sc[t] += y;
        __syncthreads();
    }
    if (t < nch) csum[t] = sc[t] - v;   // exclusive prefix
}

__global__ void offsets_kernel(const int* __restrict__ cnt, const int* __restrict__ csum,
                               int* __restrict__ offs, int N) {
    __shared__ int sc[256];
    int t = threadIdx.x;
    int i = blockIdx.x * 256 + t;
    int v = (i < N) ? cnt[i] : 0;
    sc[t] = v;
    __syncthreads();
    for (int off = 1; off < 256; off <<= 1) {
        int y = (t >= off) ? sc[t - off] : 0;
        __syncthreads();
        sc[t] += y;
        __syncthreads();
    }
    if (i < N) offs[i] = csum[blockIdx.x] + sc[t] - v;  // global exclusive prefix
}

__global__ void scatter_kernel(const int* __restrict__ dst, int* __restrict__ offs,
                               int* __restrict__ bucket, int E) {
    int i = blockIdx.x * blockDim.x + threadIdx.x;
    if (i < E) {
        int pos = atomicAdd(&offs[dst[i]], 1);
        bucket[pos] = i;
    }
}

// ---------------------------------------------------------------------------
// Kernel B: he_b3 -- PURE STREAMING B3e matvec. wave-per-edge-quad, ILP=4.
// No gathers, no butterfly, no alpha: just he_partial = bB3 + WB3 @ e_row,
// written to the e_out region. __launch_bounds__(256,2): VGPR cap 128 so the
// 64-VGPR wb3 row is truly register-resident (R9's cap-85 config gave
// VGPR=56 => WB3 re-streamed every iteration).
// ---------------------------------------------------------------------------
__global__ void __launch_bounds__(256, 2)
he_b3(const float* __restrict__ e,
      const float* __restrict__ WB3, const float* __restrict__ bB3,
      float* __restrict__ he_out, int E)
{
    const int lane = threadIdx.x & 63;
    const int wid = __builtin_amdgcn_readfirstlane((int)(threadIdx.x >> 6));
    const int wpb = blockDim.x >> 6;
    const int gw = blockIdx.x * wpb + wid;
    const int nw = gridDim.x * wpb;

    float4 wb3[16];
    const float4* w4 = (const float4*)(WB3 + (size_t)lane * D);
#pragma unroll
    for (int j = 0; j < 16; ++j) wb3[j] = w4[j];
    const float bb3 = bB3[lane];

    for (int ed = gw * 4; ed < E; ed += nw * 4) {
        int id[4];
#pragma unroll
        for (int i = 0; i < 4; ++i) id[i] = (ed + i < E) ? ed + i : E - 1;

        float hb[4];
#pragma unroll
        for (int i = 0; i < 4; ++i) hb[i] = bb3;
#pragma unroll
        for (int j = 0; j < 16; ++j) {
#pragma unroll
            for (int i = 0; i < 4; ++i) {
                float4 ev = ((const float4*)(e + (size_t)id[i] * D))[j];
                hb[i] += ev.x*wb3[j].x + ev.y*wb3[j].y + ev.z*wb3[j].z + ev.w*wb3[j].w;
            }
        }
#pragma unroll
        for (int i = 0; i < 4; ++i)
            if (ed + i < E) he_out[(size_t)(ed + i) * D + lane] = hb[i];
    }
}

// ---------------------------------------------------------------------------
// Kernel C: MERGED edge finish + gather + finalize. wave-per-node, ILP=4.
// Per edge (cheap now -- matvec hoisted to he_b3):
//   he = he_partial[eid] + B1h[s] + B2h[n](hoisted); e_out = relu(he) in
//   place; sg = sigmoid(he); alpha = butterfly(sigmaQ[s]*sigmaK[n]);
//   accumulate {Ssig, Sv, Sp} in registers. Epilogue as R9 (verified).
// No alpha array, no separate edge pass, no he round-trip driver.
// ---------------------------------------------------------------------------
__global__ void __launch_bounds__(256, 3)
edge_gather_finalize(const int* __restrict__ bucket, const int* __restrict__ offs_end,
                     const int* __restrict__ cnt, const int* __restrict__ src,
                     const float2* __restrict__ P1, const float2* __restrict__ P2,
                     const unsigned int* __restrict__ P3u,
                     const float* __restrict__ ln_g, const float* __restrict__ ln_b,
                     float* __restrict__ he_eout, float* __restrict__ h_out,
                     float* __restrict__ p_out, int N)
{
    const int lane = threadIdx.x & 63;
    const int wid = threadIdx.x >> 6;
    const int wpb = blockDim.x >> 6;
    const float lg = ln_g[lane], lb = ln_b[lane];

    for (int n = blockIdx.x * wpb + wid; n < N; n += gridDim.x * wpb) {
        const int end = offs_end[n];
        const int deg = cnt[n];
        const int start = end - deg;
        const size_t o = (size_t)n * D + lane;

        const float2 p2n = P2[o];   // {B2h, sigmaK}, hoisted per node

        float asig = 0.f, av = 0.f, ap = 0.f;

        int k = start;
        for (; k + 3 < end; k += 4) {
            int eid[4], s[4];
#pragma unroll
            for (int i = 0; i < 4; ++i)
                eid[i] = __builtin_amdgcn_readfirstlane(bucket[k + i]);
#pragma unroll
            for (int i = 0; i < 4; ++i)
                s[i] = __builtin_amdgcn_readfirstlane(src[eid[i]]);

            float2 p1[4]; unsigned int p3[4]; float hb[4];
#pragma unroll
            for (int i = 0; i < 4; ++i) {
                p1[i] = P1[(size_t)s[i] * D + lane];       // {B1h, sigmaQ}
                p3[i] = P3u[(size_t)s[i] * D + lane];      // bf16 {vh, C2p}
                hb[i] = he_eout[(size_t)eid[i] * D + lane]; // B3e partial
            }

            float sg[4], pr[4];
#pragma unroll
            for (int i = 0; i < 4; ++i) {
                float he = hb[i] + p1[i].x + p2n.x;
                he_eout[(size_t)eid[i] * D + lane] = fmaxf(he, 0.f);
                sg[i] = 1.f / (1.f + expf(-he));
                pr[i] = p1[i].y * p2n.y;
            }
#pragma unroll
            for (int off = 32; off > 0; off >>= 1) {
#pragma unroll
                for (int i = 0; i < 4; ++i) pr[i] += __shfl_xor(pr[i], off);
            }
#pragma unroll
            for (int i = 0; i < 4; ++i) {
                asig += sg[i];
                av   += sg[i] * pr[i] * bf_lo(p3[i]);
                ap   += sg[i] * bf_hi(p3[i]);
            }
        }
        for (; k < end; ++k) {
            int e0 = __builtin_amdgcn_readfirstlane(bucket[k]);
            int s0 = __builtin_amdgcn_readfirstlane(src[e0]);
            size_t eo0 = (size_t)e0 * D + lane;
            float2 p10 = P1[(size_t)s0 * D + lane];
            unsigned int p30 = P3u[(size_t)s0 * D + lane];
            float he0 = he_eout[eo0] + p10.x + p2n.x;
            he_eout[eo0] = fmaxf(he0, 0.f);
            float sg0 = 1.f / (1.f + expf(-he0));
            float pr0 = p10.y * p2n.y;
#pragma unroll
            for (int off = 32; off > 0; off >>= 1) pr0 += __shfl_xor(pr0, off);
            asig += sg0;
            av   += sg0 * pr0 * bf_lo(p30);
            ap   += sg0 * bf_hi(p30);
        }

        // fused epilogue (verified R9)
        float denom = asig + EPS;
        float vh = bf_lo(P3u[o]);
        float hv = vh + av / denom;
        hv = fmaxf(hv, 0.f);
        float su = hv;
#pragma unroll
        for (int off = 32; off > 0; off >>= 1) su += __shfl_xor(su, off);
        float mu = su * (1.f / 64.f);
        float dv = hv - mu;
        float s2 = dv * dv;
#pragma unroll
        for (int off = 32; off > 0; off >>= 1) s2 += __shfl_xor(s2, off);
        float var = s2 * (1.f / 64.f);
        h_out[o] = dv * rsqrtf(var + LN_EPS) * lg + lb;

        float pv = p_out[o] + ap / denom;   // p_out holds C1p
        p_out[o] = tanhf(pv);
    }
}

extern "C" void kernel_launch(void* const* d_in, const int* in_sizes, int n_in,
                              void* d_out, int out_size, void* d_ws, size_t ws_size,
                              hipStream_t stream) {
    const float* h    = (const float*)d_in[0];
    const float* e    = (const float*)d_in[1];
    const float* p    = (const float*)d_in[2];
    const float* WK   = (const float*)d_in[3];
    const float* bK   = (const float*)d_in[4];
    const float* WV   = (const float*)d_in[5];
    const float* bV   = (const float*)d_in[6];
    const float* WB1  = (const float*)d_in[7];
    const float* bB1  = (const float*)d_in[8];
    const float* WB2  = (const float*)d_in[9];
    const float* bB2  = (const float*)d_in[10];
    const float* WB3  = (const float*)d_in[11];
    const float* bB3  = (const float*)d_in[12];
    const float* WC1  = (const float*)d_in[13];
    const float* bC1  = (const float*)d_in[14];
    const float* WC2  = (const float*)d_in[15];
    const float* bC2  = (const float*)d_in[16];
    const float* ln_g = (const float*)d_in[17];
    const float* ln_b = (const float*)d_in[18];
    const int*   src  = (const int*)d_in[19];
    const int*   dst  = (const int*)d_in[20];

    const int N = in_sizes[0] / D;
    const int E = in_sizes[1] / D;
    const size_t ND = (size_t)N * D;

    float* out   = (float*)d_out;
    float* h_out = out;
    float* e_out = out + ND;                  // B3e partial, then relu(he)
    float* p_out = out + ND + (size_t)E * D;  // C1p, then tanh(...)

    // ws: P1 2ND + P2 2ND (f32) + P3u ND (u32)
    //   + cnt N + offs N + bucket E + csum (int)  ~= 68 MB
    float*        ws    = (float*)d_ws;
    float2*       P1    = (float2*)(ws);                // 2*ND floats
    float2*       P2    = (float2*)(ws + 2 * ND);       // 2*ND floats
    unsigned int* P3u   = (unsigned int*)(ws + 4 * ND); // ND u32
    int*          cnt   = (int*)(ws + 5 * ND);          // N ints
    int*          offs  = cnt + N;                      // N ints
    int*          bucket= offs + N;                     // E ints
    int*          csum  = bucket + E;                   // nchunk ints (<=256)

    const int nchunk = (N + 255) / 256;

    hipMemsetAsync(cnt, 0, (size_t)N * sizeof(int), stream);

    node_linears<<<(N + NT - 1) / NT, 256, 0, stream>>>(
        h, p, WK, bK, WV, bV, WB1, bB1, WB2, bB2, WC1, bC1, WC2, bC2,
        P1, P2, P3u, p_out, N);

    hist_kernel<<<(E + 255) / 256, 256, 0, stream>>>(dst, cnt, E);
    chunksum_kernel<<<nchunk, 256, 0, stream>>>(cnt, csum, N);
    scanchunk_kernel<<<1, 256, 0, stream>>>(csum, nchunk);
    offsets_kernel<<<nchunk, 256, 0, stream>>>(cnt, csum, offs, N);
    scatter_kernel<<<(E + 255) / 256, 256, 0, stream>>>(dst, offs, bucket, E);

    he_b3<<<3200, 256, 0, stream>>>(e, WB3, bB3, e_out, E);

    edge_gather_finalize<<<(N + 3) / 4, 256, 0, stream>>>(
        bucket, offs, cnt, src, P1, P2, P3u, ln_g, ln_b,
        e_out, h_out, p_out, N);
}